// Round 10
// baseline (140.326 us; speedup 1.0000x reference)
//
#include <hip/hip_runtime.h>

// Problem constants (from reference)
#define N_NODES 100000
#define N_EDGES 1600000
#define D_IN    50
#define HIDDEN  128
#define NCLS    8

// Bucket-sort parameters
#define TILE    4096
#define NTILES  ((N_EDGES + TILE - 1) / TILE)   // 391
#define BSHIFT  9
#define NB      196                              // ceil(100000 / 512)

// prep kernel block ranges
#define PREP_CONVX_BLOCKS 12500                  // N_NODES*32 / 256
#define PREP_W_BLOCKS     36                     // 9216 threads

// LDS row stride (dwords) for padded bf16 weight rows: 128 bf16 + 8 pad = 136 bf16
#define LW 68

typedef __bf16 bf16_t;
typedef bf16_t bf16x8 __attribute__((ext_vector_type(8)));
typedef float  f32x4  __attribute__((ext_vector_type(4)));

// ---------------------------------------------------------------------------
// Helpers: bf16 pack/unpack (RNE)
// ---------------------------------------------------------------------------
__device__ __forceinline__ unsigned f2bf(float f) {
    union { float f; unsigned u; } a; a.f = f;
    unsigned u = a.u;
    return (u + 0x7FFFu + ((u >> 16) & 1u)) >> 16;
}
__device__ __forceinline__ unsigned pack2(float a, float b) {
    return f2bf(a) | (f2bf(b) << 16);
}
__device__ __forceinline__ float bf_lo(unsigned v) { return __uint_as_float(v << 16); }
__device__ __forceinline__ float bf_hi(unsigned v) { return __uint_as_float(v & 0xFFFF0000u); }

// ===========================================================================
// prep: fused conv_x (xb bf16 rows + Acat x-part) | passA (bucket histogram
// + global btot atomics) | conv_w (transposed bf16 weights).
// ===========================================================================
__global__ __launch_bounds__(256) void prep_kernel(
    const float* __restrict__ x,
    const int*   __restrict__ dst,
    const float* __restrict__ W1l, const float* __restrict__ W1r,
    const float* __restrict__ W2l, const float* __restrict__ W2r,
    unsigned* __restrict__ xb, unsigned* __restrict__ acat,
    int* __restrict__ g_hist, int* __restrict__ btot,
    unsigned* __restrict__ Wt1g, unsigned* __restrict__ W2tg)
{
    __shared__ int lh[NB];
    int blk = blockIdx.x;
    int tid = threadIdx.x;

    if (blk < PREP_CONVX_BLOCKS) {
        // ---- conv_x ----
        int t = blk * 256 + tid;
        int n = t >> 5, j = t & 31;
        if (j < 25) {
            float2 v = ((const float2*)x)[n * 25 + j];
            unsigned pk = pack2(v.x, v.y);
            xb[n * 25 + j] = pk;
            acat[(size_t)n * 64 + 25 + j] = pk;
        } else {
            int z = n * 64 + 50 + (j - 25) * 2;
            acat[z] = 0u;
            acat[z + 1] = 0u;
        }
    } else if (blk < PREP_CONVX_BLOCKS + NTILES) {
        // ---- passA: per-tile bucket histogram ----
        int tile = blk - PREP_CONVX_BLOCKS;
        for (int i = tid; i < NB; i += 256) lh[i] = 0;
        __syncthreads();
        int base = tile * TILE;
        int cnt = min(TILE, N_EDGES - base);
        for (int i = tid; i < cnt; i += 256)
            atomicAdd(&lh[dst[base + i] >> BSHIFT], 1);
        __syncthreads();
        for (int i = tid; i < NB; i += 256) {
            int v = lh[i];
            g_hist[tile * NB + i] = v;
            if (v) atomicAdd(&btot[i], v);
        }
    } else {
        // ---- conv_w ----
        int t = (blk - PREP_CONVX_BLOCKS - NTILES) * 256 + tid;
        if (t < 8192) {
            int n = t >> 6, kp = t & 63;
            int k0 = kp * 2, k1 = k0 + 1;
            float v0 = (k0 < 50) ? W1l[k0 * 128 + n] : ((k0 < 100) ? W1r[(k0 - 50) * 128 + n] : 0.0f);
            float v1 = (k1 < 50) ? W1l[k1 * 128 + n] : ((k1 < 100) ? W1r[(k1 - 50) * 128 + n] : 0.0f);
            Wt1g[t] = pack2(v0, v1);
        } else if (t < 8192 + 1024) {
            int u = t - 8192;
            int n2 = u >> 6, kp = u & 63;
            int k0 = kp * 2;
            float v0 = (n2 < 8) ? W2l[k0 * 8 + n2] : W2r[k0 * 8 + n2 - 8];
            float v1 = (n2 < 8) ? W2l[(k0 + 1) * 8 + n2] : W2r[(k0 + 1) * 8 + n2 - 8];
            W2tg[u] = pack2(v0, v1);
        }
    }
}

// ===========================================================================
// passB: per-bucket exclusive scan of g_hist over tiles; then each block
// computes its own bbase[b] from btot via a parallel LDS scan (passB2 folded).
// ===========================================================================
__global__ __launch_bounds__(512) void passB_kernel(
    int* __restrict__ g_hist, const int* __restrict__ btot,
    int* __restrict__ bbase, int* __restrict__ offs)
{
    __shared__ int s[512];
    int b = blockIdx.x, tid = threadIdx.x;
    int v = (tid < NTILES) ? g_hist[tid * NB + b] : 0;
    s[tid] = v;
    __syncthreads();
    for (int d = 1; d < 512; d <<= 1) {
        int t = (tid >= d) ? s[tid - d] : 0;
        __syncthreads();
        s[tid] += t;
        __syncthreads();
    }
    if (tid < NTILES) g_hist[tid * NB + b] = s[tid] - v;   // exclusive over tiles
    __syncthreads();

    // bbase[b] = prefix sum of btot[0..b)
    int v2 = (tid < NB) ? btot[tid] : 0;
    s[tid] = v2;
    __syncthreads();
    for (int d = 1; d < 256; d <<= 1) {
        int t = (tid >= d && tid < 256) ? s[tid - d] : 0;
        __syncthreads();
        if (tid < 256) s[tid] += t;
        __syncthreads();
    }
    if (tid == b) bbase[b] = s[tid] - v2;                   // exclusive at b
    if (b == 0 && tid == 0) offs[N_NODES] = N_EDGES;
}

// ===========================================================================
// passC: reorder tile by bucket in LDS; flush PACKED edges
// (src in bits 0..16, dst_local in bits 17..25) to bk_pack.
// ===========================================================================
__global__ __launch_bounds__(256) void passC_kernel(
    const int* __restrict__ src, const int* __restrict__ dst,
    const int* __restrict__ g_hist, const int* __restrict__ bbase,
    unsigned* __restrict__ bk_pack)
{
    __shared__ int hist[NB];
    __shared__ int seg[NB];
    __shared__ int cur[NB];
    __shared__ int gof[NB];
    __shared__ int sc[256];
    __shared__ unsigned s_pack[TILE];
    __shared__ unsigned short s_bkt[TILE];

    int tid = threadIdx.x, tile = blockIdx.x;
    int base = tile * TILE;
    int cnt = min(TILE, N_EDGES - base);

    for (int i = tid; i < NB; i += 256) {
        hist[i] = 0;
        gof[i] = g_hist[tile * NB + i] + bbase[i];
    }
    __syncthreads();

    int es[16], ed[16];
    #pragma unroll
    for (int k = 0; k < 16; ++k) {
        int i = tid + k * 256;
        if (i < cnt) {
            es[k] = src[base + i];
            ed[k] = dst[base + i];
            atomicAdd(&hist[ed[k] >> BSHIFT], 1);
        }
    }
    __syncthreads();

    {
        int v = (tid < NB) ? hist[tid] : 0;
        sc[tid] = v;
        __syncthreads();
        for (int d = 1; d < 256; d <<= 1) {
            int t = (tid >= d) ? sc[tid - d] : 0;
            __syncthreads();
            sc[tid] += t;
            __syncthreads();
        }
        if (tid < NB) { seg[tid] = sc[tid] - v; cur[tid] = sc[tid] - v; }
    }
    __syncthreads();

    #pragma unroll
    for (int k = 0; k < 16; ++k) {
        int i = tid + k * 256;
        if (i < cnt) {
            int b = ed[k] >> BSHIFT;
            int p = atomicAdd(&cur[b], 1);
            s_pack[p] = (unsigned)es[k] | ((unsigned)(ed[k] & 511) << 17);
            s_bkt[p] = (unsigned short)b;
        }
    }
    __syncthreads();

    for (int i = tid; i < cnt; i += 256) {
        int b = s_bkt[i];
        int g = gof[b] + (i - seg[b]);
        bk_pack[g] = s_pack[i];
    }
}

// ===========================================================================
// passD: per-bucket CSR finalize from packed edges
// ===========================================================================
__global__ __launch_bounds__(512) void passD_kernel(
    const unsigned* __restrict__ bk_pack,
    const int* __restrict__ bbase, const int* __restrict__ btot,
    int* __restrict__ sorted_src, int* __restrict__ offs)
{
    __shared__ int ldeg[512];
    __shared__ int lofs[512];
    int b = blockIdx.x, tid = threadIdx.x;
    int ebase = bbase[b];
    int ecnt = btot[b];
    int nbase = b << BSHIFT;

    ldeg[tid] = 0;
    __syncthreads();
    for (int i = tid; i < ecnt; i += 512)
        atomicAdd(&ldeg[bk_pack[ebase + i] >> 17], 1);
    __syncthreads();

    int v = ldeg[tid];
    lofs[tid] = v;
    __syncthreads();
    for (int d = 1; d < 512; d <<= 1) {
        int t = (tid >= d) ? lofs[tid - d] : 0;
        __syncthreads();
        lofs[tid] += t;
        __syncthreads();
    }
    int ex = lofs[tid] - v;

    int node = nbase + tid;
    if (node < N_NODES) offs[node] = ebase + ex;

    ldeg[tid] = ex;
    __syncthreads();
    for (int i = tid; i < ecnt; i += 512) {
        unsigned pk = bk_pack[ebase + i];
        int p = atomicAdd(&ldeg[pk >> 17], 1);
        sorted_src[ebase + p] = (int)(pk & 0x1FFFFu);
    }
}

// ===========================================================================
// Gather-aggregate bf16 x rows. One node per HALF-WAVE (8 nodes/block),
// 8-deep unrolled edge loop -> 8 independent row-gathers in flight per lane.
// ===========================================================================
__global__ __launch_bounds__(256) void agg_x_kernel(
    const unsigned* __restrict__ xb,
    const int*      __restrict__ offs,
    const int*      __restrict__ ss,
    unsigned* __restrict__ acat)
{
    int node = blockIdx.x * 8 + (threadIdx.x >> 5);
    int dw   = threadIdx.x & 31;
    if (node >= N_NODES) return;
    int beg = offs[node], end = offs[node + 1];
    float2 a0 = {0.f,0.f}, a1 = {0.f,0.f}, a2 = {0.f,0.f}, a3 = {0.f,0.f};
    float2 a4 = {0.f,0.f}, a5 = {0.f,0.f}, a6 = {0.f,0.f}, a7 = {0.f,0.f};
    int i = beg;
    for (; i + 7 < end; i += 8) {
        int s0 = ss[i],     s1 = ss[i + 1], s2 = ss[i + 2], s3 = ss[i + 3];
        int s4 = ss[i + 4], s5 = ss[i + 5], s6 = ss[i + 6], s7 = ss[i + 7];
        if (dw < 25) {
            unsigned v0 = xb[s0 * 25 + dw];
            unsigned v1 = xb[s1 * 25 + dw];
            unsigned v2 = xb[s2 * 25 + dw];
            unsigned v3 = xb[s3 * 25 + dw];
            unsigned v4 = xb[s4 * 25 + dw];
            unsigned v5 = xb[s5 * 25 + dw];
            unsigned v6 = xb[s6 * 25 + dw];
            unsigned v7 = xb[s7 * 25 + dw];
            a0.x += bf_lo(v0); a0.y += bf_hi(v0);
            a1.x += bf_lo(v1); a1.y += bf_hi(v1);
            a2.x += bf_lo(v2); a2.y += bf_hi(v2);
            a3.x += bf_lo(v3); a3.y += bf_hi(v3);
            a4.x += bf_lo(v4); a4.y += bf_hi(v4);
            a5.x += bf_lo(v5); a5.y += bf_hi(v5);
            a6.x += bf_lo(v6); a6.y += bf_hi(v6);
            a7.x += bf_lo(v7); a7.y += bf_hi(v7);
        }
    }
    for (; i + 3 < end; i += 4) {
        int s0 = ss[i], s1 = ss[i + 1], s2 = ss[i + 2], s3 = ss[i + 3];
        if (dw < 25) {
            unsigned v0 = xb[s0 * 25 + dw];
            unsigned v1 = xb[s1 * 25 + dw];
            unsigned v2 = xb[s2 * 25 + dw];
            unsigned v3 = xb[s3 * 25 + dw];
            a0.x += bf_lo(v0); a0.y += bf_hi(v0);
            a1.x += bf_lo(v1); a1.y += bf_hi(v1);
            a2.x += bf_lo(v2); a2.y += bf_hi(v2);
            a3.x += bf_lo(v3); a3.y += bf_hi(v3);
        }
    }
    for (; i < end; ++i) {
        int s = ss[i];
        if (dw < 25) {
            unsigned v = xb[s * 25 + dw];
            a0.x += bf_lo(v); a0.y += bf_hi(v);
        }
    }
    if (dw < 25) {
        float inv = 1.0f / fmaxf((float)(end - beg), 1.0f);
        float sx = ((a0.x + a1.x) + (a2.x + a3.x)) + ((a4.x + a5.x) + (a6.x + a7.x));
        float sy = ((a0.y + a1.y) + (a2.y + a3.y)) + ((a4.y + a5.y) + (a6.y + a7.y));
        acat[(size_t)node * 64 + dw] = pack2(sx * inv, sy * inv);
    }
}

// ===========================================================================
// Fused MLP: h = relu(Acat @ W1cat + b1) via MFMA (swapped operands), then
// p = bf16(h@W2l), q = h@W2r + b2 via a second MFMA pass through LDS.
// ===========================================================================
__global__ __launch_bounds__(256) void fused_mlp_kernel(
    const unsigned* __restrict__ Acat,   // [N][64] dwords (128 bf16)
    const unsigned* __restrict__ Wt1g,   // [128][64] dwords
    const unsigned* __restrict__ W2tg,   // [16][64] dwords
    const float* __restrict__ b1,
    const float* __restrict__ b2,
    unsigned* __restrict__ pb,           // [N][4] dwords (8 bf16)
    float* __restrict__ q)               // [N][8]
{
    __shared__ unsigned sWt[128 * LW];
    __shared__ unsigned sW2t[16 * LW];
    __shared__ bf16_t   sH[4][16 * 136];

    int tid = threadIdx.x;
    for (int t = tid; t < 128 * 64; t += 256)
        sWt[(t >> 6) * LW + (t & 63)] = Wt1g[t];
    for (int t = tid; t < 16 * 64; t += 256)
        sW2t[(t >> 6) * LW + (t & 63)] = W2tg[t];
    __syncthreads();

    const int w    = tid >> 6;
    const int lane = tid & 63;
    const int lo   = lane & 15;
    const int g    = lane >> 4;

    float b1v[8][4];
    #pragma unroll
    for (int nt = 0; nt < 8; ++nt)
        #pragma unroll
        for (int r = 0; r < 4; ++r)
            b1v[nt][r] = b1[nt * 16 + g * 4 + r];
    float b2v[4];
    #pragma unroll
    for (int r = 0; r < 4; ++r)
        b2v[r] = (g >= 2) ? b2[(g - 2) * 4 + r] : 0.0f;

    bf16_t* myH = &sH[w][0];

    for (int tile = blockIdx.x; tile * 64 < N_NODES; tile += gridDim.x) {
        int node = tile * 64 + w * 16 + lo;
        int nclamp = min(node, N_NODES - 1);

        int4 bi[4];
        #pragma unroll
        for (int ks = 0; ks < 4; ++ks)
            bi[ks] = *((const int4*)(Acat + (size_t)nclamp * 64 + ks * 16 + g * 4));

        f32x4 acc[8];
        #pragma unroll
        for (int nt = 0; nt < 8; ++nt) acc[nt] = (f32x4)0.0f;
        #pragma unroll
        for (int nt = 0; nt < 8; ++nt) {
            #pragma unroll
            for (int ks = 0; ks < 4; ++ks) {
                int4 ai = *((const int4*)(sWt + (nt * 16 + lo) * LW + ks * 16 + g * 4));
                acc[nt] = __builtin_amdgcn_mfma_f32_16x16x32_bf16(
                    __builtin_bit_cast(bf16x8, ai),
                    __builtin_bit_cast(bf16x8, bi[ks]), acc[nt], 0, 0, 0);
            }
        }

        #pragma unroll
        for (int nt = 0; nt < 8; ++nt) {
            union { bf16_t h[4]; uint2 u; } pk;
            #pragma unroll
            for (int r = 0; r < 4; ++r)
                pk.h[r] = (bf16_t)fmaxf(acc[nt][r] + b1v[nt][r], 0.0f);
            *((uint2*)(myH + lo * 136 + nt * 16 + g * 4)) = pk.u;
        }
        __syncthreads();

        f32x4 acc2 = (f32x4)0.0f;
        #pragma unroll
        for (int ks = 0; ks < 4; ++ks) {
            int4 a2 = *((const int4*)(sW2t + lo * LW + ks * 16 + g * 4));
            int4 h2 = *((const int4*)(myH + lo * 136 + ks * 32 + g * 8));
            acc2 = __builtin_amdgcn_mfma_f32_16x16x32_bf16(
                __builtin_bit_cast(bf16x8, a2),
                __builtin_bit_cast(bf16x8, h2), acc2, 0, 0, 0);
        }

        if (node < N_NODES) {
            if (g < 2) {
                union { bf16_t h[4]; uint2 u; } pk;
                #pragma unroll
                for (int r = 0; r < 4; ++r) pk.h[r] = (bf16_t)acc2[r];
                *((uint2*)(pb + (size_t)node * 4 + g * 2)) = pk.u;
            } else {
                float4 qq;
                qq.x = acc2[0] + b2v[0];
                qq.y = acc2[1] + b2v[1];
                qq.z = acc2[2] + b2v[2];
                qq.w = acc2[3] + b2v[3];
                *((float4*)(q + (size_t)node * 8 + (g - 2) * 4)) = qq;
            }
        }
        __syncthreads();
    }
}

// ===========================================================================
// Gather-aggregate bf16 p rows + final: out = (sum p[src]) / max(deg,1) + q
// ===========================================================================
__global__ __launch_bounds__(256) void aggp_final_kernel(
    const unsigned* __restrict__ pb,   // [N][4] dwords (8 bf16)
    const float*    __restrict__ q,
    const int*      __restrict__ offs,
    const int*      __restrict__ ss,
    float* __restrict__ out)
{
    int node = blockIdx.x * 4 + (threadIdx.x >> 6);
    int lane = threadIdx.x & 63;
    int k  = lane >> 2;
    int c2 = lane & 3;
    if (node >= N_NODES) return;
    int beg = offs[node], end = offs[node + 1];
    float2 acc = make_float2(0.0f, 0.0f);
    int i = beg + k;
    int sNext = (i < end) ? ss[i] : 0;
    for (; i < end; i += 16) {
        int s = sNext;
        int i2 = i + 16;
        sNext = (i2 < end) ? ss[i2] : 0;
        unsigned v = pb[s * 4 + c2];
        acc.x += bf_lo(v);
        acc.y += bf_hi(v);
    }
    acc.x += __shfl_xor(acc.x, 4);  acc.y += __shfl_xor(acc.y, 4);
    acc.x += __shfl_xor(acc.x, 8);  acc.y += __shfl_xor(acc.y, 8);
    acc.x += __shfl_xor(acc.x, 16); acc.y += __shfl_xor(acc.y, 16);
    acc.x += __shfl_xor(acc.x, 32); acc.y += __shfl_xor(acc.y, 32);
    if (lane < 4) {
        float inv = 1.0f / fmaxf((float)(end - beg), 1.0f);
        float2 qq = ((const float2*)(q + (size_t)node * NCLS))[c2];
        ((float2*)(out + (size_t)node * NCLS))[c2] =
            make_float2(acc.x * inv + qq.x, acc.y * inv + qq.y);
    }
}

// ===========================================================================
extern "C" void kernel_launch(void* const* d_in, const int* in_sizes, int n_in,
                              void* d_out, int out_size, void* d_ws, size_t ws_size,
                              hipStream_t stream)
{
    const float* x   = (const float*)d_in[0];
    const int*   ei  = (const int*)  d_in[1];
    const float* W1l = (const float*)d_in[2];
    const float* W1r = (const float*)d_in[3];
    const float* b1  = (const float*)d_in[4];
    const float* W2l = (const float*)d_in[5];
    const float* W2r = (const float*)d_in[6];
    const float* b2  = (const float*)d_in[7];
    float* out = (float*)d_out;

    const int* src = ei;
    const int* dst = ei + N_EDGES;

    // Workspace layout (dword units; all segment sizes are multiples of 4)
    int* ws = (int*)d_ws;
    int*      offs       = ws;                                   // 100004
    int*      g_hist     = offs + (N_NODES + 4);                 // 76636
    int*      btot       = g_hist + NTILES * NB;                 // 256
    int*      bbase      = btot + 256;                           // 256
    int*      sorted_src = bbase + 256;                          // E
    unsigned* xb         = (unsigned*)(sorted_src + N_EDGES);    // N*25
    unsigned* Acat       = xb + (size_t)N_NODES * 25;            // N*64
    unsigned* Wt1g       = Acat + (size_t)N_NODES * 64;          // 8192
    unsigned* W2tg       = Wt1g + 8192;                          // 1024
    unsigned* pb         = W2tg + 1024;                          // N*4
    float*    q          = (float*)(pb + (size_t)N_NODES * 4);   // N*8
    unsigned* bk_pack    = (unsigned*)(q + (size_t)N_NODES * 8); // E

    // btot must be zero before prep's passA-part atomics
    (void)hipMemsetAsync(btot, 0, NB * sizeof(int), stream);

    // prep: conv_x | passA | conv_w fused
    prep_kernel<<<PREP_CONVX_BLOCKS + NTILES + PREP_W_BLOCKS, 256, 0, stream>>>(
        x, dst, W1l, W1r, W2l, W2r, xb, Acat, g_hist, btot, Wt1g, W2tg);

    // CSR build
    passB_kernel<<<NB, 512, 0, stream>>>(g_hist, btot, bbase, offs);
    passC_kernel<<<NTILES, 256, 0, stream>>>(src, dst, g_hist, bbase, bk_pack);
    passD_kernel<<<NB, 512, 0, stream>>>(bk_pack, bbase, btot, sorted_src, offs);

    // Layer 1 aggregation (writes Acat cols 0..49)
    agg_x_kernel<<<(N_NODES + 7) / 8, 256, 0, stream>>>(xb, offs, sorted_src, Acat);

    // Fused layer1 GEMM + relu + layer2 GEMMs (h stays on-chip)
    fused_mlp_kernel<<<512, 256, 0, stream>>>(Acat, Wt1g, W2tg, b1, b2, pb, q);

    // Layer 2 aggregation + final
    aggp_final_kernel<<<(N_NODES + 3) / 4, 256, 0, stream>>>(
        (const unsigned*)pb, q, offs, sorted_src, out);
}

// Round 11
// 137.177 us; speedup vs baseline: 1.0230x; 1.0230x over previous
//
#include <hip/hip_runtime.h>

// Problem constants (from reference)
#define N_NODES 100000
#define N_EDGES 1600000
#define D_IN    50
#define HIDDEN  128
#define NCLS    8

// Bucket-sort parameters
#define TILE    2048
#define NTILES  ((N_EDGES + TILE - 1) / TILE)   // 782
#define BSHIFT  9
#define NB      196                              // ceil(100000 / 512)

// prep kernel block ranges
#define PREP_CONVX_BLOCKS 12500                  // N_NODES*32 / 256
#define PREP_W_BLOCKS     36                     // 9216 threads

// LDS row stride (dwords) for padded bf16 weight rows: 128 bf16 + 8 pad = 136 bf16
#define LW 68

typedef __bf16 bf16_t;
typedef bf16_t bf16x8 __attribute__((ext_vector_type(8)));
typedef float  f32x4  __attribute__((ext_vector_type(4)));

// ---------------------------------------------------------------------------
// Helpers: bf16 pack/unpack (RNE)
// ---------------------------------------------------------------------------
__device__ __forceinline__ unsigned f2bf(float f) {
    union { float f; unsigned u; } a; a.f = f;
    unsigned u = a.u;
    return (u + 0x7FFFu + ((u >> 16) & 1u)) >> 16;
}
__device__ __forceinline__ unsigned pack2(float a, float b) {
    return f2bf(a) | (f2bf(b) << 16);
}
__device__ __forceinline__ float bf_lo(unsigned v) { return __uint_as_float(v << 16); }
__device__ __forceinline__ float bf_hi(unsigned v) { return __uint_as_float(v & 0xFFFF0000u); }

#define ACC4(a, u) { a[0]+=bf_lo(u.x); a[1]+=bf_hi(u.x); a[2]+=bf_lo(u.y); a[3]+=bf_hi(u.y); \
                     a[4]+=bf_lo(u.z); a[5]+=bf_hi(u.z); a[6]+=bf_lo(u.w); a[7]+=bf_hi(u.w); }

// ===========================================================================
// prep: fused conv_x (xb 128B bf16 rows + Acat x-part) | passA (bucket
// histogram + global btot atomics) | conv_w (transposed bf16 weights).
// ===========================================================================
__global__ __launch_bounds__(256) void prep_kernel(
    const float* __restrict__ x,
    const int*   __restrict__ dst,
    const float* __restrict__ W1l, const float* __restrict__ W1r,
    const float* __restrict__ W2l, const float* __restrict__ W2r,
    unsigned* __restrict__ xb, unsigned* __restrict__ acat,
    int* __restrict__ g_hist, int* __restrict__ btot,
    unsigned* __restrict__ Wt1g, unsigned* __restrict__ W2tg)
{
    __shared__ int lh[NB];
    int blk = blockIdx.x;
    int tid = threadIdx.x;

    if (blk < PREP_CONVX_BLOCKS) {
        // ---- conv_x: xb rows padded to 32 dwords (128B, 2 aligned lines) ----
        int t = blk * 256 + tid;
        int n = t >> 5, j = t & 31;
        if (j < 25) {
            float2 v = ((const float2*)x)[n * 25 + j];
            unsigned pk = pack2(v.x, v.y);
            xb[n * 32 + j] = pk;
            acat[(size_t)n * 64 + 25 + j] = pk;
        } else {
            xb[n * 32 + j] = 0u;
            int z = n * 64 + 50 + (j - 25) * 2;
            acat[z] = 0u;
            acat[z + 1] = 0u;
        }
    } else if (blk < PREP_CONVX_BLOCKS + NTILES) {
        // ---- passA: per-tile bucket histogram ----
        int tile = blk - PREP_CONVX_BLOCKS;
        for (int i = tid; i < NB; i += 256) lh[i] = 0;
        __syncthreads();
        int base = tile * TILE;
        int cnt = min(TILE, N_EDGES - base);
        for (int i = tid; i < cnt; i += 256)
            atomicAdd(&lh[dst[base + i] >> BSHIFT], 1);
        __syncthreads();
        for (int i = tid; i < NB; i += 256) {
            int v = lh[i];
            g_hist[tile * NB + i] = v;
            if (v) atomicAdd(&btot[i], v);
        }
    } else {
        // ---- conv_w ----
        int t = (blk - PREP_CONVX_BLOCKS - NTILES) * 256 + tid;
        if (t < 8192) {
            int n = t >> 6, kp = t & 63;
            int k0 = kp * 2, k1 = k0 + 1;
            float v0 = (k0 < 50) ? W1l[k0 * 128 + n] : ((k0 < 100) ? W1r[(k0 - 50) * 128 + n] : 0.0f);
            float v1 = (k1 < 50) ? W1l[k1 * 128 + n] : ((k1 < 100) ? W1r[(k1 - 50) * 128 + n] : 0.0f);
            Wt1g[t] = pack2(v0, v1);
        } else if (t < 8192 + 1024) {
            int u = t - 8192;
            int n2 = u >> 6, kp = u & 63;
            int k0 = kp * 2;
            float v0 = (n2 < 8) ? W2l[k0 * 8 + n2] : W2r[k0 * 8 + n2 - 8];
            float v1 = (n2 < 8) ? W2l[(k0 + 1) * 8 + n2] : W2r[(k0 + 1) * 8 + n2 - 8];
            W2tg[u] = pack2(v0, v1);
        }
    }
}

// ===========================================================================
// passB: per-bucket exclusive scan of g_hist over 782 tiles (2 per thread);
// then bbase[b] from btot via LDS scan (passB2 folded in).
// ===========================================================================
__global__ __launch_bounds__(512) void passB_kernel(
    int* __restrict__ g_hist, const int* __restrict__ btot,
    int* __restrict__ bbase, int* __restrict__ offs)
{
    __shared__ int s[512];
    int b = blockIdx.x, tid = threadIdx.x;
    int t0 = 2 * tid, t1 = 2 * tid + 1;
    int v0 = (t0 < NTILES) ? g_hist[t0 * NB + b] : 0;
    int v1 = (t1 < NTILES) ? g_hist[t1 * NB + b] : 0;
    int v = v0 + v1;
    s[tid] = v;
    __syncthreads();
    for (int d = 1; d < 512; d <<= 1) {
        int t = (tid >= d) ? s[tid - d] : 0;
        __syncthreads();
        s[tid] += t;
        __syncthreads();
    }
    int ex = s[tid] - v;
    if (t0 < NTILES) g_hist[t0 * NB + b] = ex;
    if (t1 < NTILES) g_hist[t1 * NB + b] = ex + v0;
    __syncthreads();

    // bbase[b] = prefix sum of btot[0..b)
    int v2 = (tid < NB) ? btot[tid] : 0;
    s[tid] = v2;
    __syncthreads();
    for (int d = 1; d < 512; d <<= 1) {
        int t = (tid >= d) ? s[tid - d] : 0;
        __syncthreads();
        s[tid] += t;
        __syncthreads();
    }
    if (tid == b) bbase[b] = s[tid] - v2;
    if (b == 0 && tid == 0) offs[N_NODES] = N_EDGES;
}

// ===========================================================================
// passC: reorder tile (2048 edges) by bucket in LDS; flush PACKED edges
// (src bits 0..16, dst_local bits 17..25) to bk_pack.
// ===========================================================================
__global__ __launch_bounds__(256) void passC_kernel(
    const int* __restrict__ src, const int* __restrict__ dst,
    const int* __restrict__ g_hist, const int* __restrict__ bbase,
    unsigned* __restrict__ bk_pack)
{
    __shared__ int hist[NB];
    __shared__ int seg[NB];
    __shared__ int cur[NB];
    __shared__ int gof[NB];
    __shared__ int sc[256];
    __shared__ unsigned s_pack[TILE];
    __shared__ unsigned short s_bkt[TILE];

    int tid = threadIdx.x, tile = blockIdx.x;
    int base = tile * TILE;
    int cnt = min(TILE, N_EDGES - base);

    for (int i = tid; i < NB; i += 256) {
        hist[i] = 0;
        gof[i] = g_hist[tile * NB + i] + bbase[i];
    }
    __syncthreads();

    int es[8], ed[8];
    #pragma unroll
    for (int k = 0; k < 8; ++k) {
        int i = tid + k * 256;
        if (i < cnt) {
            es[k] = src[base + i];
            ed[k] = dst[base + i];
            atomicAdd(&hist[ed[k] >> BSHIFT], 1);
        }
    }
    __syncthreads();

    {
        int v = (tid < NB) ? hist[tid] : 0;
        sc[tid] = v;
        __syncthreads();
        for (int d = 1; d < 256; d <<= 1) {
            int t = (tid >= d) ? sc[tid - d] : 0;
            __syncthreads();
            sc[tid] += t;
            __syncthreads();
        }
        if (tid < NB) { seg[tid] = sc[tid] - v; cur[tid] = sc[tid] - v; }
    }
    __syncthreads();

    #pragma unroll
    for (int k = 0; k < 8; ++k) {
        int i = tid + k * 256;
        if (i < cnt) {
            int b = ed[k] >> BSHIFT;
            int p = atomicAdd(&cur[b], 1);
            s_pack[p] = (unsigned)es[k] | ((unsigned)(ed[k] & 511) << 17);
            s_bkt[p] = (unsigned short)b;
        }
    }
    __syncthreads();

    for (int i = tid; i < cnt; i += 256) {
        int b = s_bkt[i];
        int g = gof[b] + (i - seg[b]);
        bk_pack[g] = s_pack[i];
    }
}

// ===========================================================================
// passD: per-bucket CSR finalize from packed edges
// ===========================================================================
__global__ __launch_bounds__(512) void passD_kernel(
    const unsigned* __restrict__ bk_pack,
    const int* __restrict__ bbase, const int* __restrict__ btot,
    int* __restrict__ sorted_src, int* __restrict__ offs)
{
    __shared__ int ldeg[512];
    __shared__ int lofs[512];
    int b = blockIdx.x, tid = threadIdx.x;
    int ebase = bbase[b];
    int ecnt = btot[b];
    int nbase = b << BSHIFT;

    ldeg[tid] = 0;
    __syncthreads();
    for (int i = tid; i < ecnt; i += 512)
        atomicAdd(&ldeg[bk_pack[ebase + i] >> 17], 1);
    __syncthreads();

    int v = ldeg[tid];
    lofs[tid] = v;
    __syncthreads();
    for (int d = 1; d < 512; d <<= 1) {
        int t = (tid >= d) ? lofs[tid - d] : 0;
        __syncthreads();
        lofs[tid] += t;
        __syncthreads();
    }
    int ex = lofs[tid] - v;

    int node = nbase + tid;
    if (node < N_NODES) offs[node] = ebase + ex;

    ldeg[tid] = ex;
    __syncthreads();
    for (int i = tid; i < ecnt; i += 512) {
        unsigned pk = bk_pack[ebase + i];
        int p = atomicAdd(&ldeg[pk >> 17], 1);
        sorted_src[ebase + p] = (int)(pk & 0x1FFFFu);
    }
}

// ===========================================================================
// Gather-aggregate bf16 x rows (128B-aligned rows, uint4 loads).
// One node per HALF-WAVE; lane = slot*8 + ld: 4 edge-slots x 8 uint4-lanes.
// Unroll 2 -> 8 edges in flight per half-wave, 4x fewer load instructions.
// ===========================================================================
__global__ __launch_bounds__(256) void agg_x_kernel(
    const uint4* __restrict__ xb4,     // [N][8] uint4
    const int*   __restrict__ offs,
    const int*   __restrict__ ss,
    unsigned* __restrict__ acat)
{
    int node = blockIdx.x * 8 + (threadIdx.x >> 5);
    int l32  = threadIdx.x & 31;
    int slot = l32 >> 3;      // 0..3
    int ld   = l32 & 7;       // 0..7
    if (node >= N_NODES) return;
    int beg = offs[node], end = offs[node + 1];
    float a0[8] = {0,0,0,0,0,0,0,0};
    float a1[8] = {0,0,0,0,0,0,0,0};
    int i = beg;
    for (; i + 7 < end; i += 8) {
        int s0 = ss[i + slot];
        int s1 = ss[i + slot + 4];
        uint4 u0 = xb4[s0 * 8 + ld];
        uint4 u1 = xb4[s1 * 8 + ld];
        ACC4(a0, u0);
        ACC4(a1, u1);
    }
    for (; i + 3 < end; i += 4) {
        uint4 u = xb4[ss[i + slot] * 8 + ld];
        ACC4(a0, u);
    }
    int rem = end - i;
    if (slot < rem) {
        uint4 u = xb4[ss[i + slot] * 8 + ld];
        ACC4(a1, u);
    }
    float t[8];
    #pragma unroll
    for (int k = 0; k < 8; ++k) {
        float v = a0[k] + a1[k];
        v += __shfl_xor(v, 8);
        v += __shfl_xor(v, 16);
        t[k] = v;
    }
    if (slot == 0) {
        float inv = 1.0f / fmaxf((float)(end - beg), 1.0f);
        if (ld < 6) {
            uint4 o;
            o.x = pack2(t[0] * inv, t[1] * inv);
            o.y = pack2(t[2] * inv, t[3] * inv);
            o.z = pack2(t[4] * inv, t[5] * inv);
            o.w = pack2(t[6] * inv, t[7] * inv);
            *((uint4*)(acat + (size_t)node * 64 + ld * 4)) = o;
        } else if (ld == 6) {
            acat[(size_t)node * 64 + 24] = pack2(t[0] * inv, t[1] * inv);
        }
    }
}

// ===========================================================================
// Fused MLP: h = relu(Acat @ W1cat + b1) via MFMA (swapped operands), then
// p = bf16(h@W2l), q = h@W2r + b2 via a second MFMA pass through LDS.
// ===========================================================================
__global__ __launch_bounds__(256) void fused_mlp_kernel(
    const unsigned* __restrict__ Acat,   // [N][64] dwords (128 bf16)
    const unsigned* __restrict__ Wt1g,   // [128][64] dwords
    const unsigned* __restrict__ W2tg,   // [16][64] dwords
    const float* __restrict__ b1,
    const float* __restrict__ b2,
    unsigned* __restrict__ pb,           // [N][4] dwords (8 bf16)
    float* __restrict__ q)               // [N][8]
{
    __shared__ unsigned sWt[128 * LW];
    __shared__ unsigned sW2t[16 * LW];
    __shared__ bf16_t   sH[4][16 * 136];

    int tid = threadIdx.x;
    for (int t = tid; t < 128 * 64; t += 256)
        sWt[(t >> 6) * LW + (t & 63)] = Wt1g[t];
    for (int t = tid; t < 16 * 64; t += 256)
        sW2t[(t >> 6) * LW + (t & 63)] = W2tg[t];
    __syncthreads();

    const int w    = tid >> 6;
    const int lane = tid & 63;
    const int lo   = lane & 15;
    const int g    = lane >> 4;

    float b1v[8][4];
    #pragma unroll
    for (int nt = 0; nt < 8; ++nt)
        #pragma unroll
        for (int r = 0; r < 4; ++r)
            b1v[nt][r] = b1[nt * 16 + g * 4 + r];
    float b2v[4];
    #pragma unroll
    for (int r = 0; r < 4; ++r)
        b2v[r] = (g >= 2) ? b2[(g - 2) * 4 + r] : 0.0f;

    bf16_t* myH = &sH[w][0];

    for (int tile = blockIdx.x; tile * 64 < N_NODES; tile += gridDim.x) {
        int node = tile * 64 + w * 16 + lo;
        int nclamp = min(node, N_NODES - 1);

        int4 bi[4];
        #pragma unroll
        for (int ks = 0; ks < 4; ++ks)
            bi[ks] = *((const int4*)(Acat + (size_t)nclamp * 64 + ks * 16 + g * 4));

        f32x4 acc[8];
        #pragma unroll
        for (int nt = 0; nt < 8; ++nt) acc[nt] = (f32x4)0.0f;
        #pragma unroll
        for (int nt = 0; nt < 8; ++nt) {
            #pragma unroll
            for (int ks = 0; ks < 4; ++ks) {
                int4 ai = *((const int4*)(sWt + (nt * 16 + lo) * LW + ks * 16 + g * 4));
                acc[nt] = __builtin_amdgcn_mfma_f32_16x16x32_bf16(
                    __builtin_bit_cast(bf16x8, ai),
                    __builtin_bit_cast(bf16x8, bi[ks]), acc[nt], 0, 0, 0);
            }
        }

        #pragma unroll
        for (int nt = 0; nt < 8; ++nt) {
            union { bf16_t h[4]; uint2 u; } pk;
            #pragma unroll
            for (int r = 0; r < 4; ++r)
                pk.h[r] = (bf16_t)fmaxf(acc[nt][r] + b1v[nt][r], 0.0f);
            *((uint2*)(myH + lo * 136 + nt * 16 + g * 4)) = pk.u;
        }
        __syncthreads();

        f32x4 acc2 = (f32x4)0.0f;
        #pragma unroll
        for (int ks = 0; ks < 4; ++ks) {
            int4 a2 = *((const int4*)(sW2t + lo * LW + ks * 16 + g * 4));
            int4 h2 = *((const int4*)(myH + lo * 136 + ks * 32 + g * 8));
            acc2 = __builtin_amdgcn_mfma_f32_16x16x32_bf16(
                __builtin_bit_cast(bf16x8, a2),
                __builtin_bit_cast(bf16x8, h2), acc2, 0, 0, 0);
        }

        if (node < N_NODES) {
            if (g < 2) {
                union { bf16_t h[4]; uint2 u; } pk;
                #pragma unroll
                for (int r = 0; r < 4; ++r) pk.h[r] = (bf16_t)acc2[r];
                *((uint2*)(pb + (size_t)node * 4 + g * 2)) = pk.u;
            } else {
                float4 qq;
                qq.x = acc2[0] + b2v[0];
                qq.y = acc2[1] + b2v[1];
                qq.z = acc2[2] + b2v[2];
                qq.w = acc2[3] + b2v[3];
                *((float4*)(q + (size_t)node * 8 + (g - 2) * 4)) = qq;
            }
        }
        __syncthreads();
    }
}

// ===========================================================================
// Gather-aggregate bf16 p rows + final: out = (sum p[src]) / max(deg,1) + q
// ===========================================================================
__global__ __launch_bounds__(256) void aggp_final_kernel(
    const unsigned* __restrict__ pb,   // [N][4] dwords (8 bf16)
    const float*    __restrict__ q,
    const int*      __restrict__ offs,
    const int*      __restrict__ ss,
    float* __restrict__ out)
{
    int node = blockIdx.x * 4 + (threadIdx.x >> 6);
    int lane = threadIdx.x & 63;
    int k  = lane >> 2;
    int c2 = lane & 3;
    if (node >= N_NODES) return;
    int beg = offs[node], end = offs[node + 1];
    float2 acc = make_float2(0.0f, 0.0f);
    int i = beg + k;
    int sNext = (i < end) ? ss[i] : 0;
    for (; i < end; i += 16) {
        int s = sNext;
        int i2 = i + 16;
        sNext = (i2 < end) ? ss[i2] : 0;
        unsigned v = pb[s * 4 + c2];
        acc.x += bf_lo(v);
        acc.y += bf_hi(v);
    }
    acc.x += __shfl_xor(acc.x, 4);  acc.y += __shfl_xor(acc.y, 4);
    acc.x += __shfl_xor(acc.x, 8);  acc.y += __shfl_xor(acc.y, 8);
    acc.x += __shfl_xor(acc.x, 16); acc.y += __shfl_xor(acc.y, 16);
    acc.x += __shfl_xor(acc.x, 32); acc.y += __shfl_xor(acc.y, 32);
    if (lane < 4) {
        float inv = 1.0f / fmaxf((float)(end - beg), 1.0f);
        float2 qq = ((const float2*)(q + (size_t)node * NCLS))[c2];
        ((float2*)(out + (size_t)node * NCLS))[c2] =
            make_float2(acc.x * inv + qq.x, acc.y * inv + qq.y);
    }
}

// ===========================================================================
extern "C" void kernel_launch(void* const* d_in, const int* in_sizes, int n_in,
                              void* d_out, int out_size, void* d_ws, size_t ws_size,
                              hipStream_t stream)
{
    const float* x   = (const float*)d_in[0];
    const int*   ei  = (const int*)  d_in[1];
    const float* W1l = (const float*)d_in[2];
    const float* W1r = (const float*)d_in[3];
    const float* b1  = (const float*)d_in[4];
    const float* W2l = (const float*)d_in[5];
    const float* W2r = (const float*)d_in[6];
    const float* b2  = (const float*)d_in[7];
    float* out = (float*)d_out;

    const int* src = ei;
    const int* dst = ei + N_EDGES;

    // Workspace layout (dword units; all segment sizes are multiples of 4)
    int* ws = (int*)d_ws;
    int*      offs       = ws;                                   // 100004
    int*      g_hist     = offs + (N_NODES + 4);                 // NTILES*NB = 153272 -> 153276
    int*      btot       = g_hist + (NTILES * NB + 4);           // 512
    int*      bbase      = btot + 512;                           // 512
    int*      sorted_src = bbase + 512;                          // E
    unsigned* xb         = (unsigned*)(sorted_src + N_EDGES);    // N*32 (128B rows)
    unsigned* Acat       = xb + (size_t)N_NODES * 32;            // N*64
    unsigned* Wt1g       = Acat + (size_t)N_NODES * 64;          // 8192
    unsigned* W2tg       = Wt1g + 8192;                          // 1024
    unsigned* pb         = W2tg + 1024;                          // N*4
    float*    q          = (float*)(pb + (size_t)N_NODES * 4);   // N*8
    unsigned* bk_pack    = (unsigned*)(q + (size_t)N_NODES * 8); // E

    // btot must be zero before prep's passA-part atomics
    (void)hipMemsetAsync(btot, 0, NB * sizeof(int), stream);

    // prep: conv_x | passA | conv_w fused
    prep_kernel<<<PREP_CONVX_BLOCKS + NTILES + PREP_W_BLOCKS, 256, 0, stream>>>(
        x, dst, W1l, W1r, W2l, W2r, xb, Acat, g_hist, btot, Wt1g, W2tg);

    // CSR build
    passB_kernel<<<NB, 512, 0, stream>>>(g_hist, btot, bbase, offs);
    passC_kernel<<<NTILES, 256, 0, stream>>>(src, dst, g_hist, bbase, bk_pack);
    passD_kernel<<<NB, 512, 0, stream>>>(bk_pack, bbase, btot, sorted_src, offs);

    // Layer 1 aggregation (writes Acat cols 0..49)
    agg_x_kernel<<<(N_NODES + 7) / 8, 256, 0, stream>>>(
        (const uint4*)xb, offs, sorted_src, Acat);

    // Fused layer1 GEMM + relu + layer2 GEMMs (h stays on-chip)
    fused_mlp_kernel<<<512, 256, 0, stream>>>(Acat, Wt1g, W2tg, b1, b2, pb, q);

    // Layer 2 aggregation + final
    aggp_final_kernel<<<(N_NODES + 3) / 4, 256, 0, stream>>>(
        (const unsigned*)pb, q, offs, sorted_src, out);
}

// Round 12
// 127.129 us; speedup vs baseline: 1.1038x; 1.0790x over previous
//
#include <hip/hip_runtime.h>

// Problem constants (from reference)
#define N_NODES 100000
#define N_EDGES 1600000
#define D_IN    50
#define HIDDEN  128
#define NCLS    8

// Bucket-sort parameters
#define TILE    2048
#define NTILES  ((N_EDGES + TILE - 1) / TILE)   // 782
#define BSHIFT  9
#define NB      196                              // ceil(100000 / 512)

// prep kernel block ranges
#define PREP_CONVX_BLOCKS 12500                  // N_NODES*32 / 256
#define PREP_W_BLOCKS     36                     // 9216 threads

// LDS row stride (dwords) for padded bf16 weight rows: 128 bf16 + 8 pad = 136 bf16
#define LW 68

typedef __bf16 bf16_t;
typedef bf16_t bf16x8 __attribute__((ext_vector_type(8)));
typedef float  f32x4  __attribute__((ext_vector_type(4)));

// ---------------------------------------------------------------------------
// Helpers: bf16 pack/unpack (RNE)
// ---------------------------------------------------------------------------
__device__ __forceinline__ unsigned f2bf(float f) {
    union { float f; unsigned u; } a; a.f = f;
    unsigned u = a.u;
    return (u + 0x7FFFu + ((u >> 16) & 1u)) >> 16;
}
__device__ __forceinline__ unsigned pack2(float a, float b) {
    return f2bf(a) | (f2bf(b) << 16);
}
__device__ __forceinline__ float bf_lo(unsigned v) { return __uint_as_float(v << 16); }
__device__ __forceinline__ float bf_hi(unsigned v) { return __uint_as_float(v & 0xFFFF0000u); }

#define ACC4(a, u) { a[0]+=bf_lo(u.x); a[1]+=bf_hi(u.x); a[2]+=bf_lo(u.y); a[3]+=bf_hi(u.y); \
                     a[4]+=bf_lo(u.z); a[5]+=bf_hi(u.z); a[6]+=bf_lo(u.w); a[7]+=bf_hi(u.w); }

// ===========================================================================
// prep: fused conv_x (xb 128B bf16 rows + Acat x-part) | passA (per-tile
// bucket histogram) | conv_w (transposed bf16 weights). No global atomics.
// ===========================================================================
__global__ __launch_bounds__(256) void prep_kernel(
    const float* __restrict__ x,
    const int*   __restrict__ dst,
    const float* __restrict__ W1l, const float* __restrict__ W1r,
    const float* __restrict__ W2l, const float* __restrict__ W2r,
    unsigned* __restrict__ xb, unsigned* __restrict__ acat,
    int* __restrict__ g_hist,
    unsigned* __restrict__ Wt1g, unsigned* __restrict__ W2tg)
{
    __shared__ int lh[NB];
    int blk = blockIdx.x;
    int tid = threadIdx.x;

    if (blk < PREP_CONVX_BLOCKS) {
        // ---- conv_x: xb rows padded to 32 dwords (128B, 2 aligned lines) ----
        int t = blk * 256 + tid;
        int n = t >> 5, j = t & 31;
        if (j < 25) {
            float2 v = ((const float2*)x)[n * 25 + j];
            unsigned pk = pack2(v.x, v.y);
            xb[n * 32 + j] = pk;
            acat[(size_t)n * 64 + 25 + j] = pk;
        } else {
            xb[n * 32 + j] = 0u;
            int z = n * 64 + 50 + (j - 25) * 2;
            acat[z] = 0u;
            acat[z + 1] = 0u;
        }
    } else if (blk < PREP_CONVX_BLOCKS + NTILES) {
        // ---- passA: per-tile bucket histogram ----
        int tile = blk - PREP_CONVX_BLOCKS;
        for (int i = tid; i < NB; i += 256) lh[i] = 0;
        __syncthreads();
        int base = tile * TILE;
        int cnt = min(TILE, N_EDGES - base);
        for (int i = tid; i < cnt; i += 256)
            atomicAdd(&lh[dst[base + i] >> BSHIFT], 1);
        __syncthreads();
        for (int i = tid; i < NB; i += 256)
            g_hist[tile * NB + i] = lh[i];
    } else {
        // ---- conv_w ----
        int t = (blk - PREP_CONVX_BLOCKS - NTILES) * 256 + tid;
        if (t < 8192) {
            int n = t >> 6, kp = t & 63;
            int k0 = kp * 2, k1 = k0 + 1;
            float v0 = (k0 < 50) ? W1l[k0 * 128 + n] : ((k0 < 100) ? W1r[(k0 - 50) * 128 + n] : 0.0f);
            float v1 = (k1 < 50) ? W1l[k1 * 128 + n] : ((k1 < 100) ? W1r[(k1 - 50) * 128 + n] : 0.0f);
            Wt1g[t] = pack2(v0, v1);
        } else if (t < 8192 + 1024) {
            int u = t - 8192;
            int n2 = u >> 6, kp = u & 63;
            int k0 = kp * 2;
            float v0 = (n2 < 8) ? W2l[k0 * 8 + n2] : W2r[k0 * 8 + n2 - 8];
            float v1 = (n2 < 8) ? W2l[(k0 + 1) * 8 + n2] : W2r[(k0 + 1) * 8 + n2 - 8];
            W2tg[u] = pack2(v0, v1);
        }
    }
}

// ===========================================================================
// passB: per-bucket exclusive scan of g_hist over 782 tiles (2 per thread);
// writes bucket total to btot[b] (plain store, no pre-zero needed).
// ===========================================================================
__global__ __launch_bounds__(512) void passB_kernel(
    int* __restrict__ g_hist, int* __restrict__ btot)
{
    __shared__ int s[512];
    int b = blockIdx.x, tid = threadIdx.x;
    int t0 = 2 * tid, t1 = 2 * tid + 1;
    int v0 = (t0 < NTILES) ? g_hist[t0 * NB + b] : 0;
    int v1 = (t1 < NTILES) ? g_hist[t1 * NB + b] : 0;
    int v = v0 + v1;
    s[tid] = v;
    __syncthreads();
    for (int d = 1; d < 512; d <<= 1) {
        int t = (tid >= d) ? s[tid - d] : 0;
        __syncthreads();
        s[tid] += t;
        __syncthreads();
    }
    int ex = s[tid] - v;
    if (t0 < NTILES) g_hist[t0 * NB + b] = ex;
    if (t1 < NTILES) g_hist[t1 * NB + b] = ex + v0;
    if (tid == 511) btot[b] = s[511];
}

// ===========================================================================
// passB2: single block: bbase = exclusive scan of btot; offs[N] sentinel.
// ===========================================================================
__global__ __launch_bounds__(256) void passB2_kernel(
    const int* __restrict__ btot, int* __restrict__ bbase, int* __restrict__ offs)
{
    __shared__ int s[256];
    int tid = threadIdx.x;
    int v = (tid < NB) ? btot[tid] : 0;
    s[tid] = v;
    __syncthreads();
    for (int d = 1; d < 256; d <<= 1) {
        int t = (tid >= d) ? s[tid - d] : 0;
        __syncthreads();
        s[tid] += t;
        __syncthreads();
    }
    if (tid < NB) bbase[tid] = s[tid] - v;
    if (tid == 0) offs[N_NODES] = N_EDGES;
}

// ===========================================================================
// passC: reorder tile (2048 edges) by bucket in LDS; flush PACKED edges
// (src bits 0..16, dst_local bits 17..25) to bk_pack.
// ===========================================================================
__global__ __launch_bounds__(256) void passC_kernel(
    const int* __restrict__ src, const int* __restrict__ dst,
    const int* __restrict__ g_hist, const int* __restrict__ bbase,
    unsigned* __restrict__ bk_pack)
{
    __shared__ int hist[NB];
    __shared__ int seg[NB];
    __shared__ int cur[NB];
    __shared__ int gof[NB];
    __shared__ int sc[256];
    __shared__ unsigned s_pack[TILE];
    __shared__ unsigned short s_bkt[TILE];

    int tid = threadIdx.x, tile = blockIdx.x;
    int base = tile * TILE;
    int cnt = min(TILE, N_EDGES - base);

    for (int i = tid; i < NB; i += 256) {
        hist[i] = 0;
        gof[i] = g_hist[tile * NB + i] + bbase[i];
    }
    __syncthreads();

    int es[8], ed[8];
    #pragma unroll
    for (int k = 0; k < 8; ++k) {
        int i = tid + k * 256;
        if (i < cnt) {
            es[k] = src[base + i];
            ed[k] = dst[base + i];
            atomicAdd(&hist[ed[k] >> BSHIFT], 1);
        }
    }
    __syncthreads();

    {
        int v = (tid < NB) ? hist[tid] : 0;
        sc[tid] = v;
        __syncthreads();
        for (int d = 1; d < 256; d <<= 1) {
            int t = (tid >= d) ? sc[tid - d] : 0;
            __syncthreads();
            sc[tid] += t;
            __syncthreads();
        }
        if (tid < NB) { seg[tid] = sc[tid] - v; cur[tid] = sc[tid] - v; }
    }
    __syncthreads();

    #pragma unroll
    for (int k = 0; k < 8; ++k) {
        int i = tid + k * 256;
        if (i < cnt) {
            int b = ed[k] >> BSHIFT;
            int p = atomicAdd(&cur[b], 1);
            s_pack[p] = (unsigned)es[k] | ((unsigned)(ed[k] & 511) << 17);
            s_bkt[p] = (unsigned short)b;
        }
    }
    __syncthreads();

    for (int i = tid; i < cnt; i += 256) {
        int b = s_bkt[i];
        int g = gof[b] + (i - seg[b]);
        bk_pack[g] = s_pack[i];
    }
}

// ===========================================================================
// passD: per-bucket CSR finalize from packed edges
// ===========================================================================
__global__ __launch_bounds__(512) void passD_kernel(
    const unsigned* __restrict__ bk_pack,
    const int* __restrict__ bbase, const int* __restrict__ btot,
    int* __restrict__ sorted_src, int* __restrict__ offs)
{
    __shared__ int ldeg[512];
    __shared__ int lofs[512];
    int b = blockIdx.x, tid = threadIdx.x;
    int ebase = bbase[b];
    int ecnt = btot[b];
    int nbase = b << BSHIFT;

    ldeg[tid] = 0;
    __syncthreads();
    for (int i = tid; i < ecnt; i += 512)
        atomicAdd(&ldeg[bk_pack[ebase + i] >> 17], 1);
    __syncthreads();

    int v = ldeg[tid];
    lofs[tid] = v;
    __syncthreads();
    for (int d = 1; d < 512; d <<= 1) {
        int t = (tid >= d) ? lofs[tid - d] : 0;
        __syncthreads();
        lofs[tid] += t;
        __syncthreads();
    }
    int ex = lofs[tid] - v;

    int node = nbase + tid;
    if (node < N_NODES) offs[node] = ebase + ex;

    ldeg[tid] = ex;
    __syncthreads();
    for (int i = tid; i < ecnt; i += 512) {
        unsigned pk = bk_pack[ebase + i];
        int p = atomicAdd(&ldeg[pk >> 17], 1);
        sorted_src[ebase + p] = (int)(pk & 0x1FFFFu);
    }
}

// ===========================================================================
// Gather-aggregate bf16 x rows (128B rows, uint4 loads).
// ONE NODE PER WAVE: 8 edge-slots x 8 uint4-lanes, unroll 2 ->
// 16 edges in flight, zero intra-wave divergence.
// ===========================================================================
__global__ __launch_bounds__(256) void agg_x_kernel(
    const uint4* __restrict__ xb4,     // [N][8] uint4
    const int*   __restrict__ offs,
    const int*   __restrict__ ss,
    unsigned* __restrict__ acat)
{
    int node = blockIdx.x * 4 + (threadIdx.x >> 6);
    int lane = threadIdx.x & 63;
    int slot = lane >> 3;     // 0..7 (edge slot)
    int ld   = lane & 7;      // 0..7 (uint4 within 128B row)
    if (node >= N_NODES) return;
    int beg = offs[node], end = offs[node + 1];
    float a0[8] = {0,0,0,0,0,0,0,0};
    float a1[8] = {0,0,0,0,0,0,0,0};
    int i = beg;
    for (; i + 15 < end; i += 16) {
        int s0 = ss[i + slot];
        int s1 = ss[i + slot + 8];
        uint4 u0 = xb4[s0 * 8 + ld];
        uint4 u1 = xb4[s1 * 8 + ld];
        ACC4(a0, u0);
        ACC4(a1, u1);
    }
    for (; i + 7 < end; i += 8) {
        uint4 u = xb4[ss[i + slot] * 8 + ld];
        ACC4(a0, u);
    }
    int rem = end - i;
    if (slot < rem) {
        uint4 u = xb4[ss[i + slot] * 8 + ld];
        ACC4(a1, u);
    }
    float t[8];
    #pragma unroll
    for (int k = 0; k < 8; ++k) {
        float v = a0[k] + a1[k];
        v += __shfl_xor(v, 8);
        v += __shfl_xor(v, 16);
        v += __shfl_xor(v, 32);
        t[k] = v;
    }
    if (slot == 0) {
        float inv = 1.0f / fmaxf((float)(end - beg), 1.0f);
        if (ld < 6) {
            uint4 o;
            o.x = pack2(t[0] * inv, t[1] * inv);
            o.y = pack2(t[2] * inv, t[3] * inv);
            o.z = pack2(t[4] * inv, t[5] * inv);
            o.w = pack2(t[6] * inv, t[7] * inv);
            *((uint4*)(acat + (size_t)node * 64 + ld * 4)) = o;
        } else if (ld == 6) {
            acat[(size_t)node * 64 + 24] = pack2(t[0] * inv, t[1] * inv);
        }
    }
}

// ===========================================================================
// Fused MLP: h = relu(Acat @ W1cat + b1) via MFMA (swapped operands), then
// p = bf16(h@W2l), q = h@W2r + b2 via a second MFMA pass through LDS.
// ===========================================================================
__global__ __launch_bounds__(256) void fused_mlp_kernel(
    const unsigned* __restrict__ Acat,   // [N][64] dwords (128 bf16)
    const unsigned* __restrict__ Wt1g,   // [128][64] dwords
    const unsigned* __restrict__ W2tg,   // [16][64] dwords
    const float* __restrict__ b1,
    const float* __restrict__ b2,
    unsigned* __restrict__ pb,           // [N][4] dwords (8 bf16)
    float* __restrict__ q)               // [N][8]
{
    __shared__ unsigned sWt[128 * LW];
    __shared__ unsigned sW2t[16 * LW];
    __shared__ bf16_t   sH[4][16 * 136];

    int tid = threadIdx.x;
    for (int t = tid; t < 128 * 64; t += 256)
        sWt[(t >> 6) * LW + (t & 63)] = Wt1g[t];
    for (int t = tid; t < 16 * 64; t += 256)
        sW2t[(t >> 6) * LW + (t & 63)] = W2tg[t];
    __syncthreads();

    const int w    = tid >> 6;
    const int lane = tid & 63;
    const int lo   = lane & 15;
    const int g    = lane >> 4;

    float b1v[8][4];
    #pragma unroll
    for (int nt = 0; nt < 8; ++nt)
        #pragma unroll
        for (int r = 0; r < 4; ++r)
            b1v[nt][r] = b1[nt * 16 + g * 4 + r];
    float b2v[4];
    #pragma unroll
    for (int r = 0; r < 4; ++r)
        b2v[r] = (g >= 2) ? b2[(g - 2) * 4 + r] : 0.0f;

    bf16_t* myH = &sH[w][0];

    for (int tile = blockIdx.x; tile * 64 < N_NODES; tile += gridDim.x) {
        int node = tile * 64 + w * 16 + lo;
        int nclamp = min(node, N_NODES - 1);

        int4 bi[4];
        #pragma unroll
        for (int ks = 0; ks < 4; ++ks)
            bi[ks] = *((const int4*)(Acat + (size_t)nclamp * 64 + ks * 16 + g * 4));

        f32x4 acc[8];
        #pragma unroll
        for (int nt = 0; nt < 8; ++nt) acc[nt] = (f32x4)0.0f;
        #pragma unroll
        for (int nt = 0; nt < 8; ++nt) {
            #pragma unroll
            for (int ks = 0; ks < 4; ++ks) {
                int4 ai = *((const int4*)(sWt + (nt * 16 + lo) * LW + ks * 16 + g * 4));
                acc[nt] = __builtin_amdgcn_mfma_f32_16x16x32_bf16(
                    __builtin_bit_cast(bf16x8, ai),
                    __builtin_bit_cast(bf16x8, bi[ks]), acc[nt], 0, 0, 0);
            }
        }

        #pragma unroll
        for (int nt = 0; nt < 8; ++nt) {
            union { bf16_t h[4]; uint2 u; } pk;
            #pragma unroll
            for (int r = 0; r < 4; ++r)
                pk.h[r] = (bf16_t)fmaxf(acc[nt][r] + b1v[nt][r], 0.0f);
            *((uint2*)(myH + lo * 136 + nt * 16 + g * 4)) = pk.u;
        }
        __syncthreads();

        f32x4 acc2 = (f32x4)0.0f;
        #pragma unroll
        for (int ks = 0; ks < 4; ++ks) {
            int4 a2 = *((const int4*)(sW2t + lo * LW + ks * 16 + g * 4));
            int4 h2 = *((const int4*)(myH + lo * 136 + ks * 32 + g * 8));
            acc2 = __builtin_amdgcn_mfma_f32_16x16x32_bf16(
                __builtin_bit_cast(bf16x8, a2),
                __builtin_bit_cast(bf16x8, h2), acc2, 0, 0, 0);
        }

        if (node < N_NODES) {
            if (g < 2) {
                union { bf16_t h[4]; uint2 u; } pk;
                #pragma unroll
                for (int r = 0; r < 4; ++r) pk.h[r] = (bf16_t)acc2[r];
                *((uint2*)(pb + (size_t)node * 4 + g * 2)) = pk.u;
            } else {
                float4 qq;
                qq.x = acc2[0] + b2v[0];
                qq.y = acc2[1] + b2v[1];
                qq.z = acc2[2] + b2v[2];
                qq.w = acc2[3] + b2v[3];
                *((float4*)(q + (size_t)node * 8 + (g - 2) * 4)) = qq;
            }
        }
        __syncthreads();
    }
}

// ===========================================================================
// Gather-aggregate bf16 p rows + final: out = (sum p[src]) / max(deg,1) + q
// ===========================================================================
__global__ __launch_bounds__(256) void aggp_final_kernel(
    const unsigned* __restrict__ pb,   // [N][4] dwords (8 bf16)
    const float*    __restrict__ q,
    const int*      __restrict__ offs,
    const int*      __restrict__ ss,
    float* __restrict__ out)
{
    int node = blockIdx.x * 4 + (threadIdx.x >> 6);
    int lane = threadIdx.x & 63;
    int k  = lane >> 2;
    int c2 = lane & 3;
    if (node >= N_NODES) return;
    int beg = offs[node], end = offs[node + 1];
    float2 acc = make_float2(0.0f, 0.0f);
    int i = beg + k;
    int sNext = (i < end) ? ss[i] : 0;
    for (; i < end; i += 16) {
        int s = sNext;
        int i2 = i + 16;
        sNext = (i2 < end) ? ss[i2] : 0;
        unsigned v = pb[s * 4 + c2];
        acc.x += bf_lo(v);
        acc.y += bf_hi(v);
    }
    acc.x += __shfl_xor(acc.x, 4);  acc.y += __shfl_xor(acc.y, 4);
    acc.x += __shfl_xor(acc.x, 8);  acc.y += __shfl_xor(acc.y, 8);
    acc.x += __shfl_xor(acc.x, 16); acc.y += __shfl_xor(acc.y, 16);
    acc.x += __shfl_xor(acc.x, 32); acc.y += __shfl_xor(acc.y, 32);
    if (lane < 4) {
        float inv = 1.0f / fmaxf((float)(end - beg), 1.0f);
        float2 qq = ((const float2*)(q + (size_t)node * NCLS))[c2];
        ((float2*)(out + (size_t)node * NCLS))[c2] =
            make_float2(acc.x * inv + qq.x, acc.y * inv + qq.y);
    }
}

// ===========================================================================
extern "C" void kernel_launch(void* const* d_in, const int* in_sizes, int n_in,
                              void* d_out, int out_size, void* d_ws, size_t ws_size,
                              hipStream_t stream)
{
    const float* x   = (const float*)d_in[0];
    const int*   ei  = (const int*)  d_in[1];
    const float* W1l = (const float*)d_in[2];
    const float* W1r = (const float*)d_in[3];
    const float* b1  = (const float*)d_in[4];
    const float* W2l = (const float*)d_in[5];
    const float* W2r = (const float*)d_in[6];
    const float* b2  = (const float*)d_in[7];
    float* out = (float*)d_out;

    const int* src = ei;
    const int* dst = ei + N_EDGES;

    // Workspace layout (dword units; all segment sizes are multiples of 4)
    int* ws = (int*)d_ws;
    int*      offs       = ws;                                   // 100004
    int*      g_hist     = offs + (N_NODES + 4);                 // NTILES*NB + pad
    int*      btot       = g_hist + (NTILES * NB + 4);           // 512
    int*      bbase      = btot + 512;                           // 512
    int*      sorted_src = bbase + 512;                          // E
    unsigned* xb         = (unsigned*)(sorted_src + N_EDGES);    // N*32 (128B rows)
    unsigned* Acat       = xb + (size_t)N_NODES * 32;            // N*64
    unsigned* Wt1g       = Acat + (size_t)N_NODES * 64;          // 8192
    unsigned* W2tg       = Wt1g + 8192;                          // 1024
    unsigned* pb         = W2tg + 1024;                          // N*4
    float*    q          = (float*)(pb + (size_t)N_NODES * 4);   // N*8
    unsigned* bk_pack    = (unsigned*)(q + (size_t)N_NODES * 8); // E

    // prep: conv_x | passA | conv_w fused
    prep_kernel<<<PREP_CONVX_BLOCKS + NTILES + PREP_W_BLOCKS, 256, 0, stream>>>(
        x, dst, W1l, W1r, W2l, W2r, xb, Acat, g_hist, Wt1g, W2tg);

    // CSR build
    passB_kernel <<<NB, 512, 0, stream>>>(g_hist, btot);
    passB2_kernel<<<1, 256, 0, stream>>>(btot, bbase, offs);
    passC_kernel <<<NTILES, 256, 0, stream>>>(src, dst, g_hist, bbase, bk_pack);
    passD_kernel <<<NB, 512, 0, stream>>>(bk_pack, bbase, btot, sorted_src, offs);

    // Layer 1 aggregation (writes Acat cols 0..49)
    agg_x_kernel<<<(N_NODES + 3) / 4, 256, 0, stream>>>(
        (const uint4*)xb, offs, sorted_src, Acat);

    // Fused layer1 GEMM + relu + layer2 GEMMs (h stays on-chip)
    fused_mlp_kernel<<<512, 256, 0, stream>>>(Acat, Wt1g, W2tg, b1, b2, pb, q);

    // Layer 2 aggregation + final
    aggp_final_kernel<<<(N_NODES + 3) / 4, 256, 0, stream>>>(
        (const unsigned*)pb, q, offs, sorted_src, out);
}